// Round 3
// baseline (13315.181 us; speedup 1.0000x reference)
//
#include <hip/hip_runtime.h>
#include <hip/hip_bf16.h>
#include <hip/hip_cooperative_groups.h>
#include <math.h>

namespace cg = cooperative_groups;

#define B_   32
#define T_   64
#define N_   128
#define D_   64
#define C_   129
#define CK_  16
#define H_   2
#define QD_  5
#define PLM_ 768

// ---- workspace layout (float offsets) ----
constexpr int OFF_QV   = 0;                                   // 128*5
constexpr int OFF_WEFF = 640;                                 // 3*128*129*64
constexpr int OFF_BEFF = OFF_WEFF + 3*128*129*64;             // 3*128*64
constexpr int OFF_VWP  = OFF_BEFF + 3*128*64;                 // 2*129*132 (padded fp32 v_W)
constexpr int OFF_QWP  = OFF_VWP + 2*129*132;                 // 2*129*16
constexpr int OFF_KWP  = OFF_QWP + 2*129*16;                  // 2*129*16
constexpr int OFF_VTO  = OFF_KWP + 2*129*16;                  // B*N
constexpr int OFF_KT   = OFF_VTO + B_*N_;                     // 2*B*H*CK*N  (k transposed, dbl-buffered)
constexpr int OFF_VG   = OFF_KT + 2*B_*H_*CK_*N_;             // 2*B*H*N*132 (v, dbl-buffered)
// total ~22.7 MB of d_ws

// ---------------- precompute kernels ----------------

// qv[n,:] = relu(plm[n] @ pf_W1 + pf_b1) @ pf_W2 + pf_b2
__global__ void k_qv(const float* __restrict__ plm,
                     const float* __restrict__ W1,
                     const float* __restrict__ b1,
                     const float* __restrict__ W2,
                     const float* __restrict__ b2,
                     float* __restrict__ ws) {
    int n = blockIdx.x;            // 128 blocks
    int j = threadIdx.x;           // 128 threads
    __shared__ float hid[128];
    float acc = b1[j];
    for (int p = 0; p < PLM_; ++p)
        acc += plm[n*PLM_ + p] * W1[p*128 + j];
    hid[j] = fmaxf(acc, 0.f);
    __syncthreads();
    if (j < QD_) {
        float a = b2[j];
        for (int q = 0; q < 128; ++q) a += hid[q] * W2[q*QD_ + j];
        ws[OFF_QV + n*QD_ + j] = a;
    }
}

// Weff[g][n][c][o] = sum_q qv[n,q] * W_g[q][c][o];  beff[g][n][o] = sum_q qv[n,q]*b_g[q][o]
__global__ void k_weff(const float* __restrict__ rW,
                       const float* __restrict__ uW,
                       const float* __restrict__ cW,
                       const float* __restrict__ rb,
                       const float* __restrict__ ub,
                       const float* __restrict__ cb,
                       float* __restrict__ ws) {
    int g = blockIdx.x >> 7;       // 3*128 blocks
    int n = blockIdx.x & 127;
    const float* W  = (g == 0) ? rW : (g == 1) ? uW : cW;
    const float* bb = (g == 0) ? rb : (g == 1) ? ub : cb;
    float qn[QD_];
#pragma unroll
    for (int q = 0; q < QD_; ++q) qn[q] = ws[OFF_QV + n*QD_ + q];
    for (int idx = threadIdx.x; idx < C_*D_; idx += 256) {
        int cc = idx >> 6, o = idx & 63;
        float acc = 0.f;
#pragma unroll
        for (int q = 0; q < QD_; ++q) acc += qn[q] * W[(q*C_ + cc)*D_ + o];
        ws[OFF_WEFF + ((g*128 + n)*C_ + cc)*D_ + o] = acc;
    }
    if (threadIdx.x < D_) {
        int o = threadIdx.x;
        float acc = 0.f;
#pragma unroll
        for (int q = 0; q < QD_; ++q) acc += qn[q] * bb[q*D_ + o];
        ws[OFF_BEFF + (g*128 + n)*D_ + o] = acc;
    }
}

// padded copy of v_W (row stride 132) and copies of q_W/k_W into ws
__global__ void k_pack(const float* __restrict__ vW,
                       const float* __restrict__ qW,
                       const float* __restrict__ kW,
                       float* __restrict__ ws) {
    int stride = gridDim.x * blockDim.x;
    int t0 = blockIdx.x * blockDim.x + threadIdx.x;
    for (int idx = t0; idx < 2*C_*132; idx += stride) {
        int h = idx / (C_*132);
        int r = idx % (C_*132);
        int cc = r / 132, c = r % 132;
        ws[OFF_VWP + idx] = (c < C_) ? vW[(h*C_ + cc)*C_ + c] : 0.f;
    }
    for (int idx = t0; idx < 2*C_*CK_; idx += stride) {
        ws[OFF_QWP + idx] = qW[idx];
        ws[OFF_KWP + idx] = kW[idx];
    }
}

// vto[b][n] = sum_t mask[b,t,n]
__global__ void k_vto(const float* __restrict__ mask, float* __restrict__ ws) {
    int idx = blockIdx.x * blockDim.x + threadIdx.x;  // 16*256 = 4096
    if (idx < B_*N_) {
        int b = idx >> 7, n = idx & 127;
        float acc = 0.f;
        for (int t = 0; t < T_; ++t) acc += mask[(b*T_ + t)*N_ + n];
        ws[OFF_VTO + idx] = acc;
    }
}

// ---------------- main recurrent kernel (cooperative) ----------------
// 256 blocks x 512 threads; block owns (2 batch elems) x (8 nodes); h in LDS.
__global__ void __launch_bounds__(512, 1) k_main(
    const float* __restrict__ obs,
    const float* __restrict__ mask,
    const float* __restrict__ avg,
    const int* __restrict__ lengths,
    const float* __restrict__ qb,
    const float* __restrict__ kb,
    const float* __restrict__ vb,
    float* __restrict__ ws,
    float* __restrict__ out) {
    cg::grid_group grid = cg::this_grid();
    const int tid = threadIdx.x;
    const int blk = blockIdx.x;
    const int bg = blk >> 4;      // 16 batch-groups of 2
    const int rblk = blk & 15;    // 16 node-groups of 8
    const int n0 = rblk * 8;
    const int b0 = bg * 2;

    __shared__ float h_l[2][8][64];
    __shared__ float h1_l[2][8][64];
    __shared__ float comb[2][8][132];
    __shared__ float att_l[2][8][132];
    __shared__ float qf[2][2][8][16];
    __shared__ float s_l[32][128];
    __shared__ float maskL[2][128];
    __shared__ float rar_l[2][8];

    for (int i = tid; i < 2*8*64; i += 512) ((float*)h_l)[i] = 0.f;
    const int len0 = lengths[b0];
    const int len1 = lengths[b0 + 1];
    __syncthreads();

    for (int t = 0; t < T_; ++t) {
        const int par = t & 1;
        // ---- A1: masks for all nodes of our 2 b's; rar for own rows ----
        if (tid < 256) {
            int bi = tid >> 7, j = tid & 127;
            maskL[bi][j] = mask[((b0 + bi)*T_ + t)*N_ + j];
        } else if (tid < 272) {
            int t2 = tid - 256;
            int bi = t2 >> 3, il = t2 & 7;
            int b = b0 + bi, n = n0 + il;
            float a = avg[(b*T_ + t)*N_ + n];
            float vt = ws[OFF_VTO + b*N_ + n];
            rar_l[bi][il] = 0.5f * tanhf(a / (vt + 1.f));
        }
        __syncthreads();
        // ---- A2: build comb = [x(65) | h(64)] for own rows ----
        for (int idx = tid; idx < 1024; idx += 512) {
            int bi = idx >> 9, r = idx & 511, il = r >> 6, d = r & 63;
            int b = b0 + bi, n = n0 + il;
            comb[bi][il][d] = obs[((b*T_ + t)*N_ + n)*D_ + d];
            comb[bi][il][65 + d] = h_l[bi][il][d];
        }
        if (tid < 16) { int bi = tid >> 3, il = tid & 7; comb[bi][il][64] = rar_l[bi][il]; }
        __syncthreads();
        // ---- A3: q (LDS) and k (global, transposed) ----
        for (int idx = tid; idx < 1024; idx += 512) {
            int qk = idx >> 9;
            int u = idx & 511;
            int ck = u & 15, il = (u >> 4) & 7, h = (u >> 7) & 1, bi = (u >> 8) & 1;
            int b = b0 + bi;
            const float* Wp = ws + (qk ? OFF_KWP : OFF_QWP) + h*C_*CK_ + ck;
            float acc = qk ? kb[h*CK_ + ck] : qb[h*CK_ + ck];
            const float* cb2 = comb[bi][il];
#pragma unroll 4
            for (int cc = 0; cc < C_; ++cc) acc += cb2[cc] * Wp[cc*CK_];
            if (qk == 0) qf[bi][h][il][ck] = acc;
            else ws[OFF_KT + (((par*B_ + b)*H_ + h)*CK_ + ck)*N_ + (n0 + il)] = acc;
        }
        // ---- A4: v rows -> global ----
        for (int idx = tid; idx < 1056; idx += 512) {
            int cg4 = (idx % 33) * 4;
            int u = idx / 33;
            int il = u & 7, h = (u >> 3) & 1, bi = u >> 4;
            int b = b0 + bi;
            int cq = cg4 >> 2;
            float4 acc;
            acc.x = (cg4 + 0 < C_) ? vb[h*C_ + cg4 + 0] : 0.f;
            acc.y = (cg4 + 1 < C_) ? vb[h*C_ + cg4 + 1] : 0.f;
            acc.z = (cg4 + 2 < C_) ? vb[h*C_ + cg4 + 2] : 0.f;
            acc.w = (cg4 + 3 < C_) ? vb[h*C_ + cg4 + 3] : 0.f;
            const float* cb2 = comb[bi][il];
            const float4* Wv = (const float4*)(ws + OFF_VWP + h*C_*132);
#pragma unroll 4
            for (int cc = 0; cc < C_; ++cc) {
                float cm = cb2[cc];
                float4 wv = Wv[cc*33 + cq];
                acc.x += cm*wv.x; acc.y += cm*wv.y; acc.z += cm*wv.z; acc.w += cm*wv.w;
            }
            *(float4*)(ws + OFF_VG + (((par*B_ + b)*H_ + h)*N_ + (n0 + il))*132 + cg4) = acc;
        }
        __threadfence();
        grid.sync();
        // ---- B1: scores, leaky-relu, mask ----
        for (int p = 0; p < 8; ++p) {
            int idx = tid + p*512;
            int j = idx & 127, u = idx >> 7;
            int il = u & 7, h = (u >> 3) & 1, bi = u >> 4;
            int b = b0 + bi, ig = n0 + il;
            const float* kt = ws + OFF_KT + (((par*B_ + b)*H_ + h)*CK_)*N_ + j;
            float acc = 0.f;
#pragma unroll
            for (int ck = 0; ck < CK_; ++ck) acc += qf[bi][h][il][ck] * kt[ck*N_];
            acc *= 0.25f;                       // 1/sqrt(CK)
            acc = acc > 0.f ? acc : 0.2f*acc;   // leaky relu
            if (ig != j && (maskL[bi][ig] == 0.f || maskL[bi][j] == 0.f)) acc = -9.0e15f;
            s_l[u][j] = acc;
        }
        __syncthreads();
        // ---- B2: row softmax (one wave handles 4 rows) ----
        {
            int wave = tid >> 6, lane = tid & 63;
            for (int u = wave*4; u < wave*4 + 4; ++u) {
                float x0 = s_l[u][lane], x1 = s_l[u][lane + 64];
                float m = fmaxf(x0, x1);
                for (int off = 32; off > 0; off >>= 1) m = fmaxf(m, __shfl_xor(m, off, 64));
                float e0 = __expf(x0 - m), e1 = __expf(x1 - m);
                float s = e0 + e1;
                for (int off = 32; off > 0; off >>= 1) s += __shfl_xor(s, off, 64);
                float inv = 1.f / s;
                s_l[u][lane] = e0*inv;
                s_l[u][lane + 64] = e1*inv;
            }
        }
        __syncthreads();
        // ---- B3: att = 0.5 * sum_h P_h @ V_h ----
        for (int idx = tid; idx < 528; idx += 512) {
            int cg4 = (idx % 33) * 4;
            int u = idx / 33;   // 0..15
            int il = u & 7, bi = u >> 3;
            int b = b0 + bi;
            int cq = cg4 >> 2;
            float4 acc = {0.f, 0.f, 0.f, 0.f};
#pragma unroll
            for (int h = 0; h < H_; ++h) {
                const float* pr = s_l[(bi << 4) | (h << 3) | il];
                const float4* vg = (const float4*)(ws + OFF_VG + (((par*B_ + b)*H_ + h)*N_)*132);
#pragma unroll 4
                for (int j = 0; j < N_; ++j) {
                    float pp = pr[j];
                    float4 v4 = vg[j*33 + cq];
                    acc.x += pp*v4.x; acc.y += pp*v4.y; acc.z += pp*v4.z; acc.w += pp*v4.w;
                }
            }
            att_l[bi][il][cg4 + 0] = 0.5f*acc.x;
            att_l[bi][il][cg4 + 1] = 0.5f*acc.y;
            att_l[bi][il][cg4 + 2] = 0.5f*acc.z;
            att_l[bi][il][cg4 + 3] = 0.5f*acc.w;
        }
        __syncthreads();
        // ---- C1: reset/update gates; h1 ----
        int un = tid >> 5, o2 = (tid & 31) * 2;
        int bi_c = un >> 3, il_c = un & 7;
        int b_c = b0 + bi_c, n_c = n0 + il_c;
        float ugx, ugy, h1x, h1y;
        bool ob;
        {
            const float* WR = ws + OFF_WEFF + ((0*128 + n_c)*C_)*D_ + o2;
            const float* WU = ws + OFF_WEFF + ((1*128 + n_c)*C_)*D_ + o2;
            float2 aR = *(const float2*)(ws + OFF_BEFF + (0*128 + n_c)*D_ + o2);
            float2 aU = *(const float2*)(ws + OFF_BEFF + (1*128 + n_c)*D_ + o2);
            const float* al = att_l[bi_c][il_c];
#pragma unroll 4
            for (int cc = 0; cc < C_; ++cc) {
                float a = al[cc];
                float2 wr = *(const float2*)(WR + cc*D_);
                float2 wu = *(const float2*)(WU + cc*D_);
                aR.x += a*wr.x; aR.y += a*wr.y;
                aU.x += a*wu.x; aU.y += a*wu.y;
            }
            float rx = 1.f/(1.f + __expf(-aR.x)), ry = 1.f/(1.f + __expf(-aR.y));
            ugx = 1.f/(1.f + __expf(-aU.x));  ugy = 1.f/(1.f + __expf(-aU.y));
            ob = maskL[bi_c][n_c] > 0.f;
            float hx = h_l[bi_c][il_c][o2], hy = h_l[bi_c][il_c][o2 + 1];
            h1x = ob ? rx*hx : hx;
            h1y = ob ? ry*hy : hy;
            h1_l[bi_c][il_c][o2] = h1x;
            h1_l[bi_c][il_c][o2 + 1] = h1y;
        }
        __syncthreads();
        // ---- C2: candidate; h2; output ----
        {
            const float* WC = ws + OFF_WEFF + ((2*128 + n_c)*C_)*D_ + o2;
            float2 aC = *(const float2*)(ws + OFF_BEFF + (2*128 + n_c)*D_ + o2);
            const float* cb2 = comb[bi_c][il_c];
            const float* h1r = h1_l[bi_c][il_c];
#pragma unroll 4
            for (int cc = 0; cc < 65; ++cc) {
                float z = cb2[cc];
                float2 wc = *(const float2*)(WC + cc*D_);
                aC.x += z*wc.x; aC.y += z*wc.y;
            }
#pragma unroll 4
            for (int cc = 65; cc < C_; ++cc) {
                float z = h1r[cc - 65];
                float2 wc = *(const float2*)(WC + cc*D_);
                aC.x += z*wc.x; aC.y += z*wc.y;
            }
            float cx = tanhf(aC.x), cy = tanhf(aC.y);
            float h2x = ob ? (1.f - ugx)*h1x + ugx*cx : h1x;
            float h2y = ob ? (1.f - ugy)*h1y + ugy*cy : h1y;
            h_l[bi_c][il_c][o2] = h2x;
            h_l[bi_c][il_c][o2 + 1] = h2y;
            int tf = (bi_c ? len1 : len0) - 1;
            if (t == tf) {
                float2 o2v; o2v.x = h2x; o2v.y = h2y;
                *(float2*)(out + (b_c*N_ + n_c)*D_ + o2) = o2v;
            }
        }
        __syncthreads();
    }
}

extern "C" void kernel_launch(void* const* d_in, const int* in_sizes, int n_in,
                              void* d_out, int out_size, void* d_ws, size_t ws_size,
                              hipStream_t stream) {
    (void)in_sizes; (void)n_in; (void)out_size; (void)ws_size;
    const float* obs   = (const float*)d_in[0];
    const float* mask  = (const float*)d_in[1];
    const float* avg   = (const float*)d_in[2];
    const float* plm   = (const float*)d_in[3];
    const int*   lens  = (const int*)d_in[4];
    // d_in[5] rarity_W: value-irrelevant (only zero-pattern of cur_adj is used)
    const float* pfW1  = (const float*)d_in[6];
    const float* pfb1  = (const float*)d_in[7];
    const float* pfW2  = (const float*)d_in[8];
    const float* pfb2  = (const float*)d_in[9];
    // d_in[10..13] pg_*: dead (adjacency values never compared except ==0; softmax>0 always)
    const float* rstW  = (const float*)d_in[14];
    const float* rstb  = (const float*)d_in[15];
    const float* updW  = (const float*)d_in[16];
    const float* updb  = (const float*)d_in[17];
    const float* candW = (const float*)d_in[18];
    const float* candb = (const float*)d_in[19];
    const float* qW    = (const float*)d_in[20];
    const float* qb    = (const float*)d_in[21];
    const float* kW    = (const float*)d_in[22];
    const float* kb    = (const float*)d_in[23];
    const float* vW    = (const float*)d_in[24];
    const float* vb    = (const float*)d_in[25];
    float* ws  = (float*)d_ws;
    float* out = (float*)d_out;

    hipLaunchKernelGGL(k_qv,   dim3(128), dim3(128), 0, stream, plm, pfW1, pfb1, pfW2, pfb2, ws);
    hipLaunchKernelGGL(k_weff, dim3(384), dim3(256), 0, stream, rstW, updW, candW, rstb, updb, candb, ws);
    hipLaunchKernelGGL(k_pack, dim3(64),  dim3(256), 0, stream, vW, qW, kW, ws);
    hipLaunchKernelGGL(k_vto,  dim3(16),  dim3(256), 0, stream, mask, ws);

    void* args[] = {(void*)&obs, (void*)&mask, (void*)&avg, (void*)&lens,
                    (void*)&qb, (void*)&kb, (void*)&vb, (void*)&ws, (void*)&out};
    hipLaunchCooperativeKernel((void*)k_main, dim3(256), dim3(512), args, 0, stream);
}

// Round 5
// 10835.349 us; speedup vs baseline: 1.2289x; 1.2289x over previous
//
#include <hip/hip_runtime.h>
#include <hip/hip_bf16.h>
#include <hip/hip_cooperative_groups.h>
#include <math.h>

namespace cg = cooperative_groups;

#define B_   32
#define T_   64
#define N_   128
#define D_   64
#define C_   129
#define CK_  16
#define H_   2
#define QD_  5
#define PLM_ 768

// ---- workspace layout (float offsets) ----
constexpr int OFF_QV   = 0;                                   // 128*5
constexpr int OFF_WEFF = 640;                                 // 3*128*129*64  [g][n][cc][o]
constexpr int OFF_BEFF = OFF_WEFF + 3*128*129*64;             // 3*128*64
constexpr int OFF_VWP  = OFF_BEFF + 3*128*64;                 // 2*129*132 padded fp32 v_W [h][cc][c pad132]
constexpr int OFF_VTO  = OFF_VWP + 2*129*132;                 // B*N
constexpr int OFF_KT   = OFF_VTO + B_*N_;                     // 2*B*H*N*CK  [par][b][h][j][ck]
constexpr int OFF_VG   = OFF_KT + 2*B_*H_*N_*CK_;             // 2*B*H*N*132 [par][b][h][j][c pad132] (as float4 rows of 33)
// end ~22.6 MB of d_ws

// ---------------- precompute kernels ----------------

__global__ void k_qv(const float* __restrict__ plm,
                     const float* __restrict__ W1,
                     const float* __restrict__ b1,
                     const float* __restrict__ W2,
                     const float* __restrict__ b2,
                     float* __restrict__ ws) {
    int n = blockIdx.x;            // 128 blocks
    int j = threadIdx.x;           // 128 threads
    __shared__ float hid[128];
    float acc = b1[j];
    for (int p = 0; p < PLM_; ++p)
        acc += plm[n*PLM_ + p] * W1[p*128 + j];
    hid[j] = fmaxf(acc, 0.f);
    __syncthreads();
    if (j < QD_) {
        float a = b2[j];
        for (int q = 0; q < 128; ++q) a += hid[q] * W2[q*QD_ + j];
        ws[OFF_QV + n*QD_ + j] = a;
    }
}

// WEFF[g][n][cc][o] = sum_q qv[n,q] * W_g[q][cc][o];  beff[g][n][o]
__global__ void k_weff(const float* __restrict__ rW,
                       const float* __restrict__ uW,
                       const float* __restrict__ cW,
                       const float* __restrict__ rb,
                       const float* __restrict__ ub,
                       const float* __restrict__ cb,
                       float* __restrict__ ws) {
    int g = blockIdx.x >> 7;       // 3*128 blocks
    int n = blockIdx.x & 127;
    const float* W  = (g == 0) ? rW : (g == 1) ? uW : cW;
    const float* bb = (g == 0) ? rb : (g == 1) ? ub : cb;
    float qn[QD_];
#pragma unroll
    for (int q = 0; q < QD_; ++q) qn[q] = ws[OFF_QV + n*QD_ + q];
    for (int idx = threadIdx.x; idx < C_*D_; idx += 256) {
        int cc = idx >> 6, o = idx & 63;
        float acc = 0.f;
#pragma unroll
        for (int q = 0; q < QD_; ++q) acc += qn[q] * W[(q*C_ + cc)*D_ + o];
        ws[OFF_WEFF + ((g*128 + n)*C_ + cc)*D_ + o] = acc;
    }
    if (threadIdx.x < D_) {
        int o = threadIdx.x;
        float acc = 0.f;
#pragma unroll
        for (int q = 0; q < QD_; ++q) acc += qn[q] * bb[q*D_ + o];
        ws[OFF_BEFF + (g*128 + n)*D_ + o] = acc;
    }
}

// padded copy of v_W (row stride 132, pad 0)
__global__ void k_pack(const float* __restrict__ vW, float* __restrict__ ws) {
    int stride = gridDim.x * blockDim.x;
    int t0 = blockIdx.x * blockDim.x + threadIdx.x;
    for (int idx = t0; idx < 2*C_*132; idx += stride) {
        int h = idx / (C_*132);
        int r = idx % (C_*132);
        int cc = r / 132, c = r % 132;
        ws[OFF_VWP + idx] = (c < C_) ? vW[(h*C_ + cc)*C_ + c] : 0.f;
    }
}

// vto[b][n] = sum_t mask[b,t,n]
__global__ void k_vto(const float* __restrict__ mask, float* __restrict__ ws) {
    int idx = blockIdx.x * blockDim.x + threadIdx.x;  // 16*256 = 4096
    if (idx < B_*N_) {
        int b = idx >> 7, n = idx & 127;
        float acc = 0.f;
        for (int t = 0; t < T_; ++t) acc += mask[(b*T_ + t)*N_ + n];
        ws[OFF_VTO + idx] = acc;
    }
}

// ---------------- main recurrent kernel (cooperative) ----------------
// 256 blocks x 512 threads (1 block/CU, proven-launchable shape);
// block owns 2 batch elems x 8 nodes; h in LDS. LDS ~48 KB.
__global__ void __launch_bounds__(512, 2) k_main(
    const float* __restrict__ obs,
    const float* __restrict__ mask,
    const float* __restrict__ avg,
    const int* __restrict__ lengths,
    const float* __restrict__ qW,
    const float* __restrict__ qb,
    const float* __restrict__ kW,
    const float* __restrict__ kb,
    const float* __restrict__ vb,
    float* __restrict__ ws,
    float* __restrict__ out) {
    cg::grid_group grid = cg::this_grid();
    const int tid = threadIdx.x;
    const int blk = blockIdx.x;
    const int b0 = (blk >> 4) * 2;   // 16 batch-groups of 2
    const int n0 = (blk & 15) * 8;   // 16 node-groups of 8

    __shared__ __align__(16) float h_l[2][8][64];
    __shared__ __align__(16) float comb[2][8][132];   // [x65|h64|pad3=0]
    __shared__ __align__(16) float att2[2][2][8][132];// [bi][h][il][c]
    __shared__ __align__(16) float qf[2][2][8][16];   // [bi][h][il][ck]
    __shared__ __align__(16) float s_l[32][130];      // row pad->130 (bank-conflict-free col reads)
    __shared__ float maskL[2][128];
    __shared__ float rar_l[2][8];

    ((float*)h_l)[tid] = 0.f;
    ((float*)h_l)[tid + 512] = 0.f;
    if (tid < 48) { int bi = tid / 24, r = tid % 24; comb[bi][r / 3][129 + r % 3] = 0.f; }
    const int len0 = lengths[b0];
    const int len1 = lengths[b0 + 1];
    __syncthreads();

    const float4* VWP4 = (const float4*)(ws + OFF_VWP);
    const float4* KT4  = (const float4*)(ws + OFF_KT);
    float4*       VG4  = (float4*)(ws + OFF_VG);

    for (int t = 0; t < T_; ++t) {
        const int par = t & 1;
        // ---- A1: masks + rarity ----
        if (tid < 256) {
            int bi = tid >> 7, j = tid & 127;
            maskL[bi][j] = mask[((b0 + bi)*T_ + t)*N_ + j];
        } else if (tid < 272) {
            int t2 = tid - 256, bi = t2 >> 3, il = t2 & 7;
            int b = b0 + bi, n = n0 + il;
            float a = avg[(b*T_ + t)*N_ + n];
            rar_l[bi][il] = 0.5f * tanhf(a / (ws[OFF_VTO + b*N_ + n] + 1.f));
        }
        __syncthreads();
        // ---- A2: comb = [x | h] ----
        for (int idx = tid; idx < 1024; idx += 512) {
            int bi = idx >> 9, r = idx & 511, il = r >> 6, d = r & 63;
            comb[bi][il][d] = obs[(((b0 + bi)*T_ + t)*N_ + n0 + il)*D_ + d];
            comb[bi][il][65 + d] = h_l[bi][il][d];
            if (d == 0) comb[bi][il][64] = rar_l[bi][il];
        }
        __syncthreads();
        // ---- A3: q -> LDS, k -> global [j][ck]; weights read wave-broadcast from global ----
        for (int p = 0; p < 2; ++p) {
            int idx = tid + p*512;
            int ck = idx & 15, il = (idx >> 4) & 7, h = (idx >> 7) & 1, bi = (idx >> 8) & 1, qk = idx >> 9;
            const float* Wl = (qk ? kW : qW) + h*(C_*CK_) + ck;
            float acc = qk ? kb[h*CK_ + ck] : qb[h*CK_ + ck];
            const float* cb2 = comb[bi][il];
#pragma unroll 8
            for (int cc = 0; cc < C_; ++cc) acc += cb2[cc] * Wl[cc*CK_];
            if (!qk) qf[bi][h][il][ck] = acc;
            else ws[OFF_KT + (((par*B_ + b0 + bi)*H_ + h)*N_ + n0 + il)*CK_ + ck] = acc;
        }
        // ---- A4: v rows -> global; lanes 0-15 share Wv address (broadcast), one pass over VWP ----
        for (int idx = tid; idx < 1056; idx += 512) {
            int w = idx & 15, r = idx >> 4;         // w: (bi,il), r: 0..65
            int bi = w >> 3, il = w & 7;
            int c4 = r % 33, h = r / 33;
            int c = c4 * 4;
            float4 acc;
            acc.x = (c + 0 < C_) ? vb[h*C_ + c + 0] : 0.f;
            acc.y = (c + 1 < C_) ? vb[h*C_ + c + 1] : 0.f;
            acc.z = (c + 2 < C_) ? vb[h*C_ + c + 2] : 0.f;
            acc.w = (c + 3 < C_) ? vb[h*C_ + c + 3] : 0.f;
            const float* cb2 = comb[bi][il];
#pragma unroll 8
            for (int cc = 0; cc < C_; ++cc) {
                float cm = cb2[cc];
                float4 wv = VWP4[(h*C_ + cc)*33 + c4];
                acc.x += cm*wv.x; acc.y += cm*wv.y; acc.z += cm*wv.z; acc.w += cm*wv.w;
            }
            VG4[(((par*B_ + b0 + bi)*H_ + h)*N_ + n0 + il)*33 + c4] = acc;
        }
        __threadfence();
        grid.sync();
        // ---- B1: scores ----
        {
            int j = tid & 127, h = (tid >> 7) & 1, g2 = tid >> 8;
            float mj_0 = maskL[0][j], mj_1 = maskL[1][j];
#pragma unroll
            for (int bi = 0; bi < 2; ++bi) {
                const float4* kt = &KT4[(((par*B_ + b0 + bi)*H_ + h)*N_ + j)*4];
                float4 k0 = kt[0], k1 = kt[1], k2 = kt[2], k3 = kt[3];
                float mj = bi ? mj_1 : mj_0;
#pragma unroll
                for (int r = 0; r < 4; ++r) {
                    int il = g2*4 + r, ig = n0 + il, u = bi*16 + h*8 + il;
                    const float4* qp = (const float4*)qf[bi][h][il];
                    float4 q0 = qp[0], q1 = qp[1], q2 = qp[2], q3 = qp[3];
                    float acc = q0.x*k0.x + q0.y*k0.y + q0.z*k0.z + q0.w*k0.w
                              + q1.x*k1.x + q1.y*k1.y + q1.z*k1.z + q1.w*k1.w
                              + q2.x*k2.x + q2.y*k2.y + q2.z*k2.z + q2.w*k2.w
                              + q3.x*k3.x + q3.y*k3.y + q3.z*k3.z + q3.w*k3.w;
                    acc *= 0.25f;
                    acc = acc > 0.f ? acc : 0.2f*acc;
                    if (ig != j && (maskL[bi][ig] == 0.f || mj == 0.f)) acc = -9.0e15f;
                    s_l[u][j] = acc;
                }
            }
        }
        __syncthreads();
        // ---- B2: row softmax (8 waves x 4 rows) ----
        {
            int wave = tid >> 6, lane = tid & 63;
#pragma unroll
            for (int r = 0; r < 4; ++r) {
                int u = wave*4 + r;
                float x0 = s_l[u][lane], x1 = s_l[u][lane + 64];
                float m = fmaxf(x0, x1);
                for (int off = 32; off > 0; off >>= 1) m = fmaxf(m, __shfl_xor(m, off, 64));
                float e0 = __expf(x0 - m), e1 = __expf(x1 - m);
                float s = e0 + e1;
                for (int off = 32; off > 0; off >>= 1) s += __shfl_xor(s, off, 64);
                float inv = 1.f / s;
                s_l[u][lane] = e0*inv;
                s_l[u][lane + 64] = e1*inv;
            }
        }
        __syncthreads();
        // ---- B3: att2[bi][h] = P @ V; vg reads 8-lane broadcast ----
        for (int idx = tid; idx < 1056; idx += 512) {
            int w = idx & 15, r = idx >> 4;
            int bi = w >> 3, il = w & 7;
            int c4 = r % 33, h = r / 33;
            const float* pr = s_l[bi*16 + h*8 + il];
            const float4* vg = &VG4[(((par*B_ + b0 + bi)*H_ + h)*N_)*33];
            float4 acc = {0.f, 0.f, 0.f, 0.f};
#pragma unroll 8
            for (int j = 0; j < N_; ++j) {
                float pp = pr[j];
                float4 v4 = vg[j*33 + c4];
                acc.x += pp*v4.x; acc.y += pp*v4.y; acc.z += pp*v4.z; acc.w += pp*v4.w;
            }
            ((float4*)att2[bi][h][il])[c4] = acc;
        }
        __syncthreads();
        // ---- C0: merge heads: att2[bi][0] = 0.5*(att2[bi][0]+att2[bi][1]) ----
        if (tid < 528) {
            int w = tid & 15, c4 = tid >> 4;
            int bi = w >> 3, il = w & 7;
            float4 a0 = ((float4*)att2[bi][0][il])[c4];
            float4 a1 = ((float4*)att2[bi][1][il])[c4];
            a0.x = 0.5f*(a0.x + a1.x); a0.y = 0.5f*(a0.y + a1.y);
            a0.z = 0.5f*(a0.z + a1.z); a0.w = 0.5f*(a0.w + a1.w);
            ((float4*)att2[bi][0][il])[c4] = a0;
        }
        __syncthreads();
        // ---- C1: reset/update gates (both batches per thread); h1 -> comb ----
        int il_c = tid >> 6, o = tid & 63;
        int n_c = n0 + il_c;
        float ug0, ug1, h10, h11;
        bool ob0, ob1;
        {
            const float* WR = ws + OFF_WEFF + ((0*128 + n_c)*C_)*D_ + o;
            const float* WU = ws + OFF_WEFF + ((1*128 + n_c)*C_)*D_ + o;
            const float* A0 = att2[0][0][il_c];
            const float* A1 = att2[1][0][il_c];
            float r0 = ws[OFF_BEFF + (0*128 + n_c)*D_ + o], r1 = r0;
            float u0 = ws[OFF_BEFF + (1*128 + n_c)*D_ + o], u1 = u0;
#pragma unroll 8
            for (int cc = 0; cc < C_; ++cc) {
                float wr = WR[cc*D_], wu = WU[cc*D_];
                float a0 = A0[cc], a1 = A1[cc];
                r0 += a0*wr; r1 += a1*wr;
                u0 += a0*wu; u1 += a1*wu;
            }
            float rr0 = 1.f/(1.f + __expf(-r0)), rr1 = 1.f/(1.f + __expf(-r1));
            ug0 = 1.f/(1.f + __expf(-u0));  ug1 = 1.f/(1.f + __expf(-u1));
            ob0 = maskL[0][n_c] > 0.f;
            ob1 = maskL[1][n_c] > 0.f;
            float hx0 = h_l[0][il_c][o], hx1 = h_l[1][il_c][o];
            h10 = ob0 ? rr0*hx0 : hx0;
            h11 = ob1 ? rr1*hx1 : hx1;
            comb[0][il_c][65 + o] = h10;
            comb[1][il_c][65 + o] = h11;
        }
        __syncthreads();
        // ---- C2: candidate; h2; output ----
        {
            const float* WC = ws + OFF_WEFF + ((2*128 + n_c)*C_)*D_ + o;
            const float* Z0 = comb[0][il_c];
            const float* Z1 = comb[1][il_c];
            float c0 = ws[OFF_BEFF + (2*128 + n_c)*D_ + o], c1 = c0;
#pragma unroll 8
            for (int cc = 0; cc < C_; ++cc) {
                float wc = WC[cc*D_];
                c0 += Z0[cc]*wc; c1 += Z1[cc]*wc;
            }
            float cand0 = tanhf(c0), cand1 = tanhf(c1);
            float h20 = ob0 ? (1.f - ug0)*h10 + ug0*cand0 : h10;
            float h21 = ob1 ? (1.f - ug1)*h11 + ug1*cand1 : h11;
            h_l[0][il_c][o] = h20;
            h_l[1][il_c][o] = h21;
            if (t == len0 - 1) out[((b0    )*N_ + n_c)*D_ + o] = h20;
            if (t == len1 - 1) out[((b0 + 1)*N_ + n_c)*D_ + o] = h21;
        }
        __syncthreads();
    }
}

extern "C" void kernel_launch(void* const* d_in, const int* in_sizes, int n_in,
                              void* d_out, int out_size, void* d_ws, size_t ws_size,
                              hipStream_t stream) {
    (void)in_sizes; (void)n_in; (void)out_size; (void)ws_size;
    const float* obs   = (const float*)d_in[0];
    const float* mask  = (const float*)d_in[1];
    const float* avg   = (const float*)d_in[2];
    const float* plm   = (const float*)d_in[3];
    const int*   lens  = (const int*)d_in[4];
    // d_in[5] rarity_W: value-irrelevant (only zero-pattern of cur_adj is used)
    const float* pfW1  = (const float*)d_in[6];
    const float* pfb1  = (const float*)d_in[7];
    const float* pfW2  = (const float*)d_in[8];
    const float* pfb2  = (const float*)d_in[9];
    // d_in[10..13] pg_*: dead (adjacency values only tested ==0; softmax>0 always)
    const float* rstW  = (const float*)d_in[14];
    const float* rstb  = (const float*)d_in[15];
    const float* updW  = (const float*)d_in[16];
    const float* updb  = (const float*)d_in[17];
    const float* candW = (const float*)d_in[18];
    const float* candb = (const float*)d_in[19];
    const float* qW    = (const float*)d_in[20];
    const float* qb    = (const float*)d_in[21];
    const float* kW    = (const float*)d_in[22];
    const float* kb    = (const float*)d_in[23];
    const float* vW    = (const float*)d_in[24];
    const float* vb    = (const float*)d_in[25];
    float* ws  = (float*)d_ws;
    float* out = (float*)d_out;

    hipLaunchKernelGGL(k_qv,   dim3(128), dim3(128), 0, stream, plm, pfW1, pfb1, pfW2, pfb2, ws);
    hipLaunchKernelGGL(k_weff, dim3(384), dim3(256), 0, stream, rstW, updW, candW, rstb, updb, candb, ws);
    hipLaunchKernelGGL(k_pack, dim3(64),  dim3(256), 0, stream, vW, ws);
    hipLaunchKernelGGL(k_vto,  dim3(16),  dim3(256), 0, stream, mask, ws);

    void* args[] = {(void*)&obs, (void*)&mask, (void*)&avg, (void*)&lens,
                    (void*)&qW, (void*)&qb, (void*)&kW, (void*)&kb, (void*)&vb,
                    (void*)&ws, (void*)&out};
    hipLaunchCooperativeKernel((void*)k_main, dim3(256), dim3(512), args, 0, stream);
}